// Round 1
// baseline (789.459 us; speedup 1.0000x reference)
//
#include <hip/hip_runtime.h>

typedef __bf16 bf16x8 __attribute__((ext_vector_type(8)));
typedef float floatx4 __attribute__((ext_vector_type(4)));
typedef unsigned short u16;

__device__ __forceinline__ u16 f2bf(float f) {
    union { float f; unsigned int u; } q; q.f = f;
    unsigned int r = q.u + 0x7FFFu + ((q.u >> 16) & 1u);
    return (u16)(r >> 16);
}
__device__ __forceinline__ float bf2f(u16 b) {
    union { unsigned int u; float f; } q; q.u = ((unsigned int)b) << 16;
    return q.f;
}

// ---------------- prep kernels ----------------

__global__ __launch_bounds__(256) void bn_prep(
    const float* __restrict__ gk, const float* __restrict__ bk,
    const float* __restrict__ mk, const float* __restrict__ vk,
    const float* __restrict__ gs, const float* __restrict__ bs,
    const float* __restrict__ ms, const float* __restrict__ vs,
    const float* __restrict__ gh, const float* __restrict__ bh,
    const float* __restrict__ mh, const float* __restrict__ vh,
    float* __restrict__ par)  // [sck|shk|scs|shs|sch|shh] x 256 floats
{
    int i = threadIdx.x;
    float s;
    s = gk[i] * rsqrtf(vk[i] + 1e-5f); par[0*256+i] = s; par[1*256+i] = bk[i] - mk[i]*s;
    s = gs[i] * rsqrtf(vs[i] + 1e-5f); par[2*256+i] = s; par[3*256+i] = bs[i] - ms[i]*s;
    s = gh[i] * rsqrtf(vh[i] + 1e-5f); par[4*256+i] = s; par[5*256+i] = bh[i] - mh[i]*s;
}

// OIHW [256,256,3,3] fp32 -> [o][(r*3+c)*256 + ci] bf16  (k-contiguous per out-channel)
__global__ __launch_bounds__(256) void pack3x3(const float* __restrict__ w, u16* __restrict__ out) {
    int tid = blockIdx.x * 256 + threadIdx.x;   // 589824 total, exact grid
    int o  = tid / 2304;
    int k  = tid - o * 2304;
    int rc = k >> 8;
    int ci = k & 255;
    out[tid] = f2bf(w[o * 2304 + ci * 9 + rc]);
}

__global__ __launch_bounds__(256) void cast_bf16(const float* __restrict__ in, u16* __restrict__ out, int n) {
    int tid = blockIdx.x * 256 + threadIdx.x;
    if (tid < n) out[tid] = f2bf(in[tid]);
}

// NCHW fp32 -> NHWC bf16, C=256
__global__ __launch_bounds__(256) void nchw2nhwc(const float* __restrict__ in, u16* __restrict__ out,
                                                 int HW, int n) {
    int tid = blockIdx.x * 256 + threadIdx.x;
    if (tid >= n) return;
    int ci = tid & 255;
    int p  = tid >> 8;
    int b  = p / HW;
    int sp = p - b * HW;
    out[tid] = f2bf(in[((size_t)b * 256 + ci) * HW + sp]);
}

// ---------------- conv as implicit GEMM (bf16 MFMA) ----------------
// A: NHWC bf16 input, gathered with tap shifts. W: [Ntot][Ktot] k-contiguous.
// Out[m][n] = relu(scale[n] * sum_k A*W + shift[n]), m = b*OHW + y*OW + x.
#define LDK 40   // 32 + 8 pad (elements): row stride 80 B balances LDS banks

__global__ __launch_bounds__(256) void conv_gemm(
    const u16* __restrict__ Ain, const u16* __restrict__ Wpk,
    const float* __restrict__ scale, const float* __restrict__ shift,
    u16* __restrict__ Out,
    int OHW, int OW, int IW, int bstride, int Cin, int KW, int nrc, int Ntot)
{
    __shared__ u16 Alds[128 * LDK];
    __shared__ u16 Blds[128 * LDK];

    const int t  = threadIdx.x;
    const int m0 = blockIdx.x * 128;
    const int n0 = blockIdx.y * 128;

    // staging assignment: thread -> (row, 16-element chunk)
    const int arow   = t >> 1;
    const int achunk = (t & 1) << 4;

    int m   = m0 + arow;
    int bb  = m / OHW;
    int rem = m - bb * OHW;
    int yy  = rem / OW;
    int xx  = rem - yy * OW;
    const u16* aptr = Ain + (size_t)bb * bstride + (size_t)(yy * IW + xx) * Cin + achunk;
    const int Ktot = nrc * Cin;
    const u16* bptr = Wpk + (size_t)(n0 + arow) * Ktot + achunk;

    floatx4 zero = {0.f, 0.f, 0.f, 0.f};
    floatx4 acc[4][4];
#pragma unroll
    for (int i = 0; i < 4; ++i)
#pragma unroll
        for (int j = 0; j < 4; ++j) acc[i][j] = zero;

    const int lane = t & 63;
    const int wave = t >> 6;
    const int wr   = (wave >> 1) << 6;
    const int wc   = (wave & 1) << 6;
    const int quad = lane >> 4;
    const int lrow = lane & 15;
    const int awoff = arow * LDK + achunk;

    for (int rc = 0; rc < nrc; ++rc) {
        int r = rc / KW;
        int c = rc - r * KW;
        const u16* ap = aptr + (r * IW + c) * Cin;
        const u16* bp = bptr + rc * Cin;
        for (int ci0 = 0; ci0 < Cin; ci0 += 32) {
            int4 av0 = *(const int4*)(ap + ci0);
            int4 av1 = *(const int4*)(ap + ci0 + 8);
            int4 bv0 = *(const int4*)(bp + ci0);
            int4 bv1 = *(const int4*)(bp + ci0 + 8);
            __syncthreads();
            *(int4*)&Alds[awoff]     = av0;
            *(int4*)&Alds[awoff + 8] = av1;
            *(int4*)&Blds[awoff]     = bv0;
            *(int4*)&Blds[awoff + 8] = bv1;
            __syncthreads();
            bf16x8 af[4], bfr[4];
#pragma unroll
            for (int mi = 0; mi < 4; ++mi)
                af[mi] = *(const bf16x8*)&Alds[(wr + mi * 16 + lrow) * LDK + (quad << 3)];
#pragma unroll
            for (int ni = 0; ni < 4; ++ni)
                bfr[ni] = *(const bf16x8*)&Blds[(wc + ni * 16 + lrow) * LDK + (quad << 3)];
#pragma unroll
            for (int mi = 0; mi < 4; ++mi)
#pragma unroll
                for (int ni = 0; ni < 4; ++ni)
                    acc[mi][ni] = __builtin_amdgcn_mfma_f32_16x16x32_bf16(af[mi], bfr[ni], acc[mi][ni], 0, 0, 0);
        }
    }

    float sc[4], sh[4];
#pragma unroll
    for (int ni = 0; ni < 4; ++ni) {
        int gn = n0 + wc + ni * 16 + lrow;
        sc[ni] = scale[gn];
        sh[ni] = shift[gn];
    }
#pragma unroll
    for (int mi = 0; mi < 4; ++mi) {
        int gm = m0 + wr + mi * 16 + (quad << 2);
#pragma unroll
        for (int ri = 0; ri < 4; ++ri) {
            size_t ro = (size_t)(gm + ri) * Ntot + n0 + wc + lrow;
#pragma unroll
            for (int ni = 0; ni < 4; ++ni) {
                float v = acc[mi][ni][ri] * sc[ni] + sh[ni];
                v = fmaxf(v, 0.f);
                Out[ro + ni * 16] = f2bf(v);
            }
        }
    }
}

// ---------------- depthwise xcorr ----------------
// f[b,y,x,ci] = sum_{r,c} ss[b,y+r,x+c,ci] * kk[b,r,c,ci]   (NHWC bf16)
__global__ __launch_bounds__(256) void xcorr(const u16* __restrict__ ss, const u16* __restrict__ kk,
                                             u16* __restrict__ f) {
    int bid = blockIdx.x;           // b*25 + y
    int b = bid / 25, y = bid - b * 25;
    int ci = threadIdx.x;
    float kv[25];
#pragma unroll
    for (int i = 0; i < 25; ++i)
        kv[i] = bf2f(kk[(size_t)(b * 25 + i) * 256 + ci]);
    const u16* sbase = ss + (size_t)(b * 29 + y) * 29 * 256 + ci;
    u16* fbase = f + (size_t)(b * 25 + y) * 25 * 256 + ci;
    for (int x = 0; x < 25; ++x) {
        float acc = 0.f;
#pragma unroll
        for (int r = 0; r < 5; ++r)
#pragma unroll
            for (int c = 0; c < 5; ++c)
                acc += bf2f(sbase[(r * 29 + x + c) * 256]) * kv[r * 5 + c];
        fbase[x * 256] = f2bf(acc);
    }
}

// ---------------- final 1x1 conv (256->20) + bias, write NCHW fp32 ----------------
__global__ __launch_bounds__(256) void head(const u16* __restrict__ h, const float* __restrict__ w2,
                                            const float* __restrict__ b2, float* __restrict__ out) {
    __shared__ u16   hl[25 * 264];   // h row tile, padded stride
    __shared__ float wl[20 * 257];   // weights, padded stride (bank-spread)
    int bid = blockIdx.x;            // b*25 + y
    int b = bid / 25, y = bid - b * 25;
    int t = threadIdx.x;
    const u16* hrow = h + (size_t)(b * 25 + y) * 25 * 256;
    for (int i = t; i < 6400; i += 256) {
        int x = i >> 8, c = i & 255;
        hl[x * 264 + c] = hrow[i];
    }
    for (int i = t; i < 5120; i += 256) {
        int co = i >> 8, c = i & 255;
        wl[co * 257 + c] = w2[i];
    }
    __syncthreads();
    for (int o = t; o < 500; o += 256) {   // o = x*20 + co
        int x = o / 20, co = o - x * 20;
        float acc = b2[co];
        const u16* hp = &hl[x * 264];
        const float* wp = &wl[co * 257];
        for (int k = 0; k < 256; ++k) acc += bf2f(hp[k]) * wp[k];
        out[(size_t)((b * 20 + co) * 25 + y) * 25 + x] = acc;
    }
}

// ---------------- workspace layout ----------------
#define OFF_SIN  0ull
#define SZ_SIN   62980096ull      // 128*31*31*256*2
#define OFF_KIN  (OFF_SIN + SZ_SIN)
#define SZ_KIN   3211264ull       // 128*7*7*256*2
#define OFF_WKP  (OFF_KIN + SZ_KIN)
#define SZ_WKP   1179648ull       // 256*2304*2
#define OFF_WSP  (OFF_WKP + SZ_WKP)
#define SZ_WSP   1179648ull
#define OFF_WH1P (OFF_WSP + SZ_WSP)
#define SZ_WH1P  131072ull        // 256*256*2
#define OFF_PAR  (OFF_WH1P + SZ_WH1P)
#define SZ_PAR   8192ull          // 6 * 256 floats (padded)
#define OFF_KK   (OFF_PAR + SZ_PAR)
#define SZ_KK    1638400ull       // 128*25*256*2
#define OFF_SS   (OFF_KK + SZ_KK)
#define SZ_SS    55115776ull      // 128*29*29*256*2
#define OFF_F    OFF_SIN          // reuse: sin dead after search conv
#define OFF_H    OFF_SS           // reuse: ss dead after xcorr

extern "C" void kernel_launch(void* const* d_in, const int* in_sizes, int n_in,
                              void* d_out, int out_size, void* d_ws, size_t ws_size,
                              hipStream_t stream) {
    const float* kin  = (const float*)d_in[0];   // [128,256,7,7]
    const float* sin_ = (const float*)d_in[1];   // [128,256,31,31]
    const float* wk   = (const float*)d_in[2];
    const float* gk   = (const float*)d_in[3];
    const float* bk   = (const float*)d_in[4];
    const float* mk   = (const float*)d_in[5];
    const float* vk   = (const float*)d_in[6];
    const float* wsw  = (const float*)d_in[7];
    const float* gs   = (const float*)d_in[8];
    const float* bs   = (const float*)d_in[9];
    const float* ms   = (const float*)d_in[10];
    const float* vs   = (const float*)d_in[11];
    const float* wh1  = (const float*)d_in[12];
    const float* gh   = (const float*)d_in[13];
    const float* bh   = (const float*)d_in[14];
    const float* mh   = (const float*)d_in[15];
    const float* vh   = (const float*)d_in[16];
    const float* wh2  = (const float*)d_in[17];
    const float* bh2  = (const float*)d_in[18];
    float* out = (float*)d_out;

    char* w = (char*)d_ws;
    u16*   SIN  = (u16*)(w + OFF_SIN);
    u16*   KIN  = (u16*)(w + OFF_KIN);
    u16*   WKP  = (u16*)(w + OFF_WKP);
    u16*   WSP  = (u16*)(w + OFF_WSP);
    u16*   WH1P = (u16*)(w + OFF_WH1P);
    float* PAR  = (float*)(w + OFF_PAR);
    u16*   KK   = (u16*)(w + OFF_KK);
    u16*   SS   = (u16*)(w + OFF_SS);
    u16*   F    = (u16*)(w + OFF_F);
    u16*   H    = (u16*)(w + OFF_H);

    // prep
    bn_prep<<<1, 256, 0, stream>>>(gk, bk, mk, vk, gs, bs, ms, vs, gh, bh, mh, vh, PAR);
    pack3x3<<<2304, 256, 0, stream>>>(wk, WKP);
    pack3x3<<<2304, 256, 0, stream>>>(wsw, WSP);
    cast_bf16<<<256, 256, 0, stream>>>(wh1, WH1P, 65536);
    nchw2nhwc<<<6272, 256, 0, stream>>>(kin, KIN, 49, 1605632);
    nchw2nhwc<<<123008, 256, 0, stream>>>(sin_, SIN, 961, 31490048);

    // kernel branch conv3x3+bn+relu: M=3200
    conv_gemm<<<dim3(25, 2), 256, 0, stream>>>(KIN, WKP, PAR + 0, PAR + 256, KK,
                                               25, 5, 7, 12544, 256, 3, 9, 256);
    // search branch conv3x3+bn+relu: M=107648
    conv_gemm<<<dim3(841, 2), 256, 0, stream>>>(SIN, WSP, PAR + 512, PAR + 768, SS,
                                                841, 29, 31, 246016, 256, 3, 9, 256);
    // depthwise xcorr
    xcorr<<<3200, 256, 0, stream>>>(SS, KK, F);
    // 1x1 conv + bn + relu: M=80000
    conv_gemm<<<dim3(625, 2), 256, 0, stream>>>(F, WH1P, PAR + 1024, PAR + 1280, H,
                                                625, 25, 25, 160000, 256, 1, 1, 256);
    // head: 1x1 conv 256->20 + bias, NCHW fp32
    head<<<3200, 256, 0, stream>>>(H, wh2, bh2, out);

    (void)in_sizes; (void)n_in; (void)out_size; (void)ws_size;
}

// Round 2
// 645.927 us; speedup vs baseline: 1.2222x; 1.2222x over previous
//
#include <hip/hip_runtime.h>

typedef __bf16 bf16x8 __attribute__((ext_vector_type(8)));
typedef float floatx4 __attribute__((ext_vector_type(4)));
typedef unsigned short u16;
typedef unsigned int u32;

__device__ __forceinline__ u16 f2bf(float f) {
    union { float f; unsigned int u; } q; q.f = f;
    unsigned int r = q.u + 0x7FFFu + ((q.u >> 16) & 1u);
    return (u16)(r >> 16);
}
__device__ __forceinline__ float bf2f(u16 b) {
    union { unsigned int u; float f; } q; q.u = ((unsigned int)b) << 16;
    return q.f;
}

// async 16B global -> LDS DMA (wave-uniform LDS base + lane*16)
__device__ __forceinline__ void gl2lds16(const u16* g, u16* l) {
    __builtin_amdgcn_global_load_lds((const __attribute__((address_space(1))) u32*)g,
                                     (__attribute__((address_space(3))) u32*)l, 16, 0, 0);
}

// ---------------- prep kernels ----------------

__global__ __launch_bounds__(256) void bn_prep(
    const float* __restrict__ gk, const float* __restrict__ bk,
    const float* __restrict__ mk, const float* __restrict__ vk,
    const float* __restrict__ gs, const float* __restrict__ bs,
    const float* __restrict__ ms, const float* __restrict__ vs,
    const float* __restrict__ gh, const float* __restrict__ bh,
    const float* __restrict__ mh, const float* __restrict__ vh,
    float* __restrict__ par)
{
    int i = threadIdx.x;
    float s;
    s = gk[i] * rsqrtf(vk[i] + 1e-5f); par[0*256+i] = s; par[1*256+i] = bk[i] - mk[i]*s;
    s = gs[i] * rsqrtf(vs[i] + 1e-5f); par[2*256+i] = s; par[3*256+i] = bs[i] - ms[i]*s;
    s = gh[i] * rsqrtf(vh[i] + 1e-5f); par[4*256+i] = s; par[5*256+i] = bh[i] - mh[i]*s;
}

// OIHW [256,256,3,3] fp32 -> [o][(r*3+c)*256 + ci] bf16
__global__ __launch_bounds__(256) void pack3x3(const float* __restrict__ w, u16* __restrict__ out) {
    int tid = blockIdx.x * 256 + threadIdx.x;
    int o  = tid / 2304;
    int k  = tid - o * 2304;
    int rc = k >> 8;
    int ci = k & 255;
    out[tid] = f2bf(w[o * 2304 + ci * 9 + rc]);
}

__global__ __launch_bounds__(256) void cast_bf16(const float* __restrict__ in, u16* __restrict__ out, int n) {
    int tid = blockIdx.x * 256 + threadIdx.x;
    if (tid < n) out[tid] = f2bf(in[tid]);
}

// NCHW fp32 -> NHWC bf16, C=256, LDS-tiled (64 ci x 32 sp), both phases coalesced
__global__ __launch_bounds__(256) void nchw2nhwc_t(const float* __restrict__ in, u16* __restrict__ out,
                                                   int HW, int sptiles) {
    __shared__ float tile[64][33];
    int bid = blockIdx.x;                // b*4*sptiles + ct*sptiles + st
    int st  = bid % sptiles;
    int tmp = bid / sptiles;
    int ct  = tmp & 3;
    int b   = tmp >> 2;
    int sp0 = st * 32, ci0 = ct * 64;
    int t = threadIdx.x;
    int j = t & 31, i8 = t >> 5;         // read: j = sp lane, i8 = ci slice
    const float* ip = in + ((size_t)b * 256 + ci0 + i8) * HW + sp0 + j;
#pragma unroll
    for (int k = 0; k < 8; ++k) {
        if (sp0 + j < HW) tile[i8 + k * 8][j] = ip[(size_t)(k * 8) * HW];
    }
    __syncthreads();
    int cl = t & 63, s4 = t >> 6;        // write: cl = ci lane, s4 = sp slice
#pragma unroll
    for (int k = 0; k < 8; ++k) {
        int spl = s4 + k * 4;
        int sp  = sp0 + spl;
        if (sp < HW) out[((size_t)b * HW + sp) * 256 + ci0 + cl] = f2bf(tile[cl][spl]);
    }
}

// ---------------- conv as implicit GEMM (bf16 MFMA, m97 structure) ----------------
// A: NHWC bf16, tap-shift gather. W: [Ntot=256][Ktot] k-contiguous.
// 128x128 tile, BK=32, global_load_lds 16B DMA, XOR-swizzled unpadded LDS.
// LDS slot s (16B = 8 elems): row = s>>2, stored k-chunk = (s&3) ^ ((s>>3)&3).
// Fragment read for (row r, quad q): elem offset = r*32 + (q ^ ((r>>1)&3))*8  -> 2-way banks (free).
__global__ __launch_bounds__(256) void conv_gemm(
    const u16* __restrict__ Ain, const u16* __restrict__ Wpk,
    const float* __restrict__ scale, const float* __restrict__ shift,
    u16* __restrict__ Out,
    int OHW, int OW, int IW, int bstride, int KW, int nrc, int mblocks)
{
    __shared__ u16 Alds[4096];
    __shared__ u16 Blds[4096];

    // XCD-contiguous remap: round-robin (lid%8 -> XCD) becomes contiguous m-ranges per XCD;
    // the two n-blocks of an m-tile stay adjacent (A-tap re-reads hit XCD-local L2).
    const int tot = mblocks * 2;
    const int grp = (tot >> 3) << 3;
    const int lid = blockIdx.x;
    const int nid = (lid < grp) ? ((lid & 7) * (grp >> 3) + (lid >> 3)) : lid;
    const int m0 = (nid >> 1) * 128;
    const int n0 = (nid & 1) * 128;

    const int t    = threadIdx.x;
    const int wave = t >> 6;
    const int lane = t & 63;
    const int quad = lane >> 4;
    const int lrow = lane & 15;

    // gather: thread t serves slots t and t+256 (same swizzled k-offset for both)
    const int koff = (((t & 3) ^ ((t >> 3) & 3)) << 3);   // elements
    const int r0 = t >> 2;
    int m_a0 = m0 + r0;
    int b0 = m_a0 / OHW; int rem0 = m_a0 - b0 * OHW; int y0 = rem0 / OW; int x0 = rem0 - y0 * OW;
    int m_a1 = m_a0 + 64;
    int b1 = m_a1 / OHW; int rem1 = m_a1 - b1 * OHW; int y1 = rem1 / OW; int x1 = rem1 - y1 * OW;
    const u16* ag0 = Ain + (size_t)b0 * bstride + (size_t)(y0 * IW + x0) * 256 + koff;
    const u16* ag1 = Ain + (size_t)b1 * bstride + (size_t)(y1 * IW + x1) * 256 + koff;
    const int Ktot = nrc * 256;
    const u16* bg0 = Wpk + (size_t)(n0 + r0) * Ktot + koff;
    const u16* bg1 = bg0 + (size_t)64 * Ktot;

    u16* lA0 = Alds + wave * 512;          // wave-uniform LDS bases (64 lanes x 16B = 1KB)
    u16* lA1 = Alds + 2048 + wave * 512;
    u16* lB0 = Blds + wave * 512;
    u16* lB1 = Blds + 2048 + wave * 512;

    floatx4 zero = {0.f, 0.f, 0.f, 0.f};
    floatx4 acc[4][4];
#pragma unroll
    for (int i = 0; i < 4; ++i)
#pragma unroll
        for (int j = 0; j < 4; ++j) acc[i][j] = zero;

    const int wr  = (wave >> 1) << 6;
    const int wc  = (wave & 1) << 6;
    const int pos = ((quad ^ ((lrow >> 1) & 3)) << 3);   // stored chunk elem offset for frag reads

    const int nchunks = nrc << 3;                        // Cin=256 -> 8 chunks per tap
    for (int ch = 0; ch < nchunks; ++ch) {
        int rc  = ch >> 3;
        int ci0 = (ch & 7) << 5;
        int rr  = rc / KW;
        int cc  = rc - rr * KW;
        int ao  = (rr * IW + cc) * 256 + ci0;            // wave-uniform (scalar)
        int bo  = ch << 5;
        __syncthreads();                                  // all frag reads of prev chunk done
        gl2lds16(ag0 + ao, lA0);
        gl2lds16(ag1 + ao, lA1);
        gl2lds16(bg0 + bo, lB0);
        gl2lds16(bg1 + bo, lB1);
        __syncthreads();                                  // vmcnt(0) drain -> DMA visible
        bf16x8 af[4], bfr[4];
#pragma unroll
        for (int mi = 0; mi < 4; ++mi)
            af[mi] = *(const bf16x8*)&Alds[(wr + mi * 16 + lrow) * 32 + pos];
#pragma unroll
        for (int ni = 0; ni < 4; ++ni)
            bfr[ni] = *(const bf16x8*)&Blds[(wc + ni * 16 + lrow) * 32 + pos];
#pragma unroll
        for (int mi = 0; mi < 4; ++mi)
#pragma unroll
            for (int ni = 0; ni < 4; ++ni)
                acc[mi][ni] = __builtin_amdgcn_mfma_f32_16x16x32_bf16(af[mi], bfr[ni], acc[mi][ni], 0, 0, 0);
    }

    float sc[4], sh[4];
#pragma unroll
    for (int ni = 0; ni < 4; ++ni) {
        int gn = n0 + wc + ni * 16 + lrow;
        sc[ni] = scale[gn];
        sh[ni] = shift[gn];
    }
#pragma unroll
    for (int mi = 0; mi < 4; ++mi) {
        int gm = m0 + wr + mi * 16 + (quad << 2);
#pragma unroll
        for (int ri = 0; ri < 4; ++ri) {
            size_t ro = (size_t)(gm + ri) * 256 + n0 + wc + lrow;
#pragma unroll
            for (int ni = 0; ni < 4; ++ni) {
                float v = acc[mi][ni][ri] * sc[ni] + sh[ni];
                v = fmaxf(v, 0.f);
                Out[ro + ni * 16] = f2bf(v);
            }
        }
    }
}

// ---------------- depthwise xcorr ----------------
__global__ __launch_bounds__(256) void xcorr(const u16* __restrict__ ss, const u16* __restrict__ kk,
                                             u16* __restrict__ f) {
    int bid = blockIdx.x;           // b*25 + y
    int b = bid / 25, y = bid - b * 25;
    int ci = threadIdx.x;
    float kv[25];
#pragma unroll
    for (int i = 0; i < 25; ++i)
        kv[i] = bf2f(kk[(size_t)(b * 25 + i) * 256 + ci]);
    const u16* sbase = ss + (size_t)(b * 29 + y) * 29 * 256 + ci;
    u16* fbase = f + (size_t)(b * 25 + y) * 25 * 256 + ci;
    for (int x = 0; x < 25; ++x) {
        float acc = 0.f;
#pragma unroll
        for (int r = 0; r < 5; ++r)
#pragma unroll
            for (int c = 0; c < 5; ++c)
                acc += bf2f(sbase[(r * 29 + x + c) * 256]) * kv[r * 5 + c];
        fbase[x * 256] = f2bf(acc);
    }
}

// ---------------- final 1x1 conv (256->20) + bias, NCHW fp32 out ----------------
__global__ __launch_bounds__(256) void head(const u16* __restrict__ h, const float* __restrict__ w2,
                                            const float* __restrict__ b2, float* __restrict__ out) {
    __shared__ u16   hl[25 * 264];
    __shared__ float wl[20 * 257];
    int bid = blockIdx.x;            // b*25 + y
    int b = bid / 25, y = bid - b * 25;
    int t = threadIdx.x;
    const u16* hrow = h + (size_t)(b * 25 + y) * 25 * 256;
    for (int i = t; i < 6400; i += 256) {
        int x = i >> 8, c = i & 255;
        hl[x * 264 + c] = hrow[i];
    }
    for (int i = t; i < 5120; i += 256) {
        int co = i >> 8, c = i & 255;
        wl[co * 257 + c] = w2[i];
    }
    __syncthreads();
    for (int o = t; o < 500; o += 256) {
        int x = o / 20, co = o - x * 20;
        float acc = b2[co];
        const u16* hp = &hl[x * 264];
        const float* wp = &wl[co * 257];
        for (int k = 0; k < 256; ++k) acc += bf2f(hp[k]) * wp[k];
        out[(size_t)((b * 20 + co) * 25 + y) * 25 + x] = acc;
    }
}

// ---------------- workspace layout ----------------
#define OFF_SIN  0ull
#define SZ_SIN   62980096ull      // 128*31*31*256*2
#define OFF_KIN  (OFF_SIN + SZ_SIN)
#define SZ_KIN   3211264ull       // 128*7*7*256*2
#define OFF_WKP  (OFF_KIN + SZ_KIN)
#define SZ_WKP   1179648ull
#define OFF_WSP  (OFF_WKP + SZ_WKP)
#define SZ_WSP   1179648ull
#define OFF_WH1P (OFF_WSP + SZ_WSP)
#define SZ_WH1P  131072ull
#define OFF_PAR  (OFF_WH1P + SZ_WH1P)
#define SZ_PAR   8192ull
#define OFF_KK   (OFF_PAR + SZ_PAR)
#define SZ_KK    1638400ull       // 128*25*256*2
#define OFF_SS   (OFF_KK + SZ_KK)
#define SZ_SS    55115776ull      // 128*29*29*256*2
#define OFF_F    OFF_SIN          // reuse: sin dead after search conv
#define OFF_H    OFF_SS           // reuse: ss dead after xcorr

extern "C" void kernel_launch(void* const* d_in, const int* in_sizes, int n_in,
                              void* d_out, int out_size, void* d_ws, size_t ws_size,
                              hipStream_t stream) {
    const float* kin  = (const float*)d_in[0];
    const float* sin_ = (const float*)d_in[1];
    const float* wk   = (const float*)d_in[2];
    const float* gk   = (const float*)d_in[3];
    const float* bk   = (const float*)d_in[4];
    const float* mk   = (const float*)d_in[5];
    const float* vk   = (const float*)d_in[6];
    const float* wsw  = (const float*)d_in[7];
    const float* gs   = (const float*)d_in[8];
    const float* bs   = (const float*)d_in[9];
    const float* ms   = (const float*)d_in[10];
    const float* vs   = (const float*)d_in[11];
    const float* wh1  = (const float*)d_in[12];
    const float* gh   = (const float*)d_in[13];
    const float* bh   = (const float*)d_in[14];
    const float* mh   = (const float*)d_in[15];
    const float* vh   = (const float*)d_in[16];
    const float* wh2  = (const float*)d_in[17];
    const float* bh2  = (const float*)d_in[18];
    float* out = (float*)d_out;

    char* w = (char*)d_ws;
    u16*   SIN  = (u16*)(w + OFF_SIN);
    u16*   KIN  = (u16*)(w + OFF_KIN);
    u16*   WKP  = (u16*)(w + OFF_WKP);
    u16*   WSP  = (u16*)(w + OFF_WSP);
    u16*   WH1P = (u16*)(w + OFF_WH1P);
    float* PAR  = (float*)(w + OFF_PAR);
    u16*   KK   = (u16*)(w + OFF_KK);
    u16*   SS   = (u16*)(w + OFF_SS);
    u16*   F    = (u16*)(w + OFF_F);
    u16*   H    = (u16*)(w + OFF_H);

    bn_prep<<<1, 256, 0, stream>>>(gk, bk, mk, vk, gs, bs, ms, vs, gh, bh, mh, vh, PAR);
    pack3x3<<<2304, 256, 0, stream>>>(wk, WKP);
    pack3x3<<<2304, 256, 0, stream>>>(wsw, WSP);
    cast_bf16<<<256, 256, 0, stream>>>(wh1, WH1P, 65536);
    // tiled transposes: grid = B * 4 ci-tiles * sp-tiles
    nchw2nhwc_t<<<128 * 4 * 2, 256, 0, stream>>>(kin, KIN, 49, 2);
    nchw2nhwc_t<<<128 * 4 * 31, 256, 0, stream>>>(sin_, SIN, 961, 31);

    // kernel branch conv3x3+bn+relu: M=3200 (25 m-blocks)
    conv_gemm<<<50, 256, 0, stream>>>(KIN, WKP, PAR + 0, PAR + 256, KK,
                                      25, 5, 7, 12544, 3, 9, 25);
    // search branch conv3x3+bn+relu: M=107648 (841 m-blocks)
    conv_gemm<<<1682, 256, 0, stream>>>(SIN, WSP, PAR + 512, PAR + 768, SS,
                                        841, 29, 31, 246016, 3, 9, 841);
    // depthwise xcorr
    xcorr<<<3200, 256, 0, stream>>>(SS, KK, F);
    // 1x1 conv + bn + relu: M=80000 (625 m-blocks)
    conv_gemm<<<1250, 256, 0, stream>>>(F, WH1P, PAR + 1024, PAR + 1280, H,
                                        625, 25, 25, 160000, 1, 1, 625);
    // head
    head<<<3200, 256, 0, stream>>>(H, wh2, bh2, out);

    (void)in_sizes; (void)n_in; (void)out_size; (void)ws_size;
}